// Round 7
// baseline (326.244 us; speedup 1.0000x reference)
//
#include <hip/hip_runtime.h>
#include <hip/hip_bf16.h>
#include <math.h>

// GNO collapsed: h = lift(x); per layer h = gelu(h@weff + beff),
//   weff = Wb + c0*(A@T' + qk su^T),  beff = bb + c0*(kq.T' + qbk su),
//   A = Wq@Wk^T, qk = Wq@bk, kq = Wk@bq, qbk = bq.bk     (G-INDEPENDENT)
//   T' = G@Wv + s bv^T,  su = Wv^T s + N bv,  G = h^T h, s = h^T 1,
//   c0 = (1/sqrt(64))/4096.
// Round 19: r18 structure with the spill fixed.
//  - r18 post-mortem: __launch_bounds__(512,2) capped VGPR at 128 -> compiler
//    spilled the matmul working set to scratch -> 550 MB/dispatch HBM traffic
//    (FETCH 294MB/WRITE 240MB), kernel became HBM-bound at 2.2 TB/s = 252us.
//    Diagnostics: VALUBusy 30->10% (scratch VMEM stalls), LDS conflicts
//    2.6M->435K (LDS ops replaced by scratch), VGPR 248->128.
//  - Fix: __launch_bounds__(512,1) -- VGPR cap 512. LDS (109.5 KB) already
//    limits to 1 block/CU = 2 waves/SIMD, which is the occupancy we wanted.
//  - Everything else identical to r18 (512 thr, split partials, 4x2 tiles,
//    2 polls/layer fabric, diagonal Wk transpose, shadow-phase E).

#define NLAYER 4
#define NB 2
#define NN 4096
#define DD 64
#define RPB 32              // rows per block (8192 rows / 256 blocks)
#define NT 512
#define NBLK 256
#define SHP 68              // padded LDS row stride (floats)
#define C0F (1.0f/32768.0f)
#define PSZ 2304            // packed partial floats: 2176 tri + 64 s + 64 pad
#define NCH 128             // combine chunks per batch
#define CHW 18              // floats per combine chunk

typedef __hip_bfloat16 bf16;
typedef unsigned long long u64t;

// ---- LDS float offsets ----
#define O_SH   0            // sH  [32][68] = 2176
#define O_B1   2176         // W1  [64][68] Wq -> Wv
#define O_B2   6528         // W2  [64][68] A
#define O_B3   10880        // B3  [64][68] PS/RED alias; G; weff
#define O_B4   15232        // W4  [64][68] Wk -> Wb
#define O_B5   19584        // W5  [64][68] WkT -> T'
#define O_PS2  23936        // PS2 [2304] second-half partial
#define O_SS   26240
#define O_SU   26304
#define O_BK   26368
#define O_BQ   26432
#define O_BV   26496
#define O_BE   26560
#define O_QK   26624
#define O_KQ   26688
#define O_QBK  26752
#define O_RED  26816        // red [8][64]
#define SM_TOT 27328        // 109312 B -> 1 block/CU (8 waves, 2/SIMD)

__device__ __forceinline__ float b2f(const bf16 v) { return __bfloat162float(v); }
__device__ __forceinline__ float bfu(unsigned s) { return __uint_as_float(s << 16); }

template <typename T> struct Acc;
template <> struct Acc<float> {
    static __device__ __forceinline__ float ld(const void* p, int i) { return ((const float*)p)[i]; }
    static __device__ __forceinline__ void st(void* p, int i, float v) { ((float*)p)[i] = v; }
};
template <> struct Acc<bf16> {
    static __device__ __forceinline__ float ld(const void* p, int i) { return b2f(((const bf16*)p)[i]); }
    static __device__ __forceinline__ void st(void* p, int i, float v) { ((bf16*)p)[i] = __float2bfloat16(v); }
};

__device__ __forceinline__ float gelu_exact(float x) {
    return 0.5f * x * (1.0f + erff(x * 0.70710678118654752f));
}

// ---- device-coherent helpers (agent scope, relaxed) ----
__device__ __forceinline__ float2 ldc2(const float* p) {
    u64t v = __hip_atomic_load((const u64t*)p, __ATOMIC_RELAXED, __HIP_MEMORY_SCOPE_AGENT);
    float2 r;
    r.x = __uint_as_float((unsigned)v);
    r.y = __uint_as_float((unsigned)(v >> 32));
    return r;
}
__device__ __forceinline__ void stc2(float* p, float a, float b) {
    u64t v = ((u64t)__float_as_uint(b) << 32) | (u64t)__float_as_uint(a);
    __hip_atomic_store((u64t*)p, v, __ATOMIC_RELAXED, __HIP_MEMORY_SCOPE_AGENT);
}
__device__ __forceinline__ unsigned ldw(unsigned* p) {
    return __hip_atomic_load(p, __ATOMIC_RELAXED, __HIP_MEMORY_SCOPE_AGENT);
}
__device__ __forceinline__ void stw(unsigned* p, unsigned v) {
    __hip_atomic_store(p, v, __ATOMIC_RELAXED, __HIP_MEMORY_SCOPE_AGENT);
}
__device__ __forceinline__ void pollw(unsigned* p, unsigned ep) {
    int guard = 0;
    while (ldw(p) < ep && ++guard < (1 << 18)) __builtin_amdgcn_s_sleep(2);
}

// acc[a][b] += sum_k L[a].k * Rk.{x,y}   (4x2 tile, K=4 step)
__device__ __forceinline__ void mm4x2(float (&acc)[4][2],
    float4 L0, float4 L1, float4 L2, float4 L3,
    float2 R0, float2 R1, float2 R2, float2 R3)
{
    const float L[4][4] = {{L0.x,L0.y,L0.z,L0.w},{L1.x,L1.y,L1.z,L1.w},
                           {L2.x,L2.y,L2.z,L2.w},{L3.x,L3.y,L3.z,L3.w}};
    const float Rx[4] = {R0.x, R1.x, R2.x, R3.x};
    const float Ry[4] = {R0.y, R1.y, R2.y, R3.y};
    #pragma unroll
    for (int a = 0; a < 4; a++)
        #pragma unroll
        for (int k = 0; k < 4; k++) {
            acc[a][0] += L[a][k] * Rx[k];
            acc[a][1] += L[a][k] * Ry[k];
        }
}

// acc[a][b] += A.a * B.b
__device__ __forceinline__ void outer4x4(float (&acc)[4][4], float4 A, float4 B)
{
    const float Aa[4] = {A.x, A.y, A.z, A.w};
    const float Ba[4] = {B.x, B.y, B.z, B.w};
    #pragma unroll
    for (int a = 0; a < 4; a++)
        #pragma unroll
        for (int b = 0; b < 4; b++)
            acc[a][b] += Aa[a] * Ba[b];
}

template <typename T>
__device__ void run_net(
    const void* x, const void* lw, const void* lb,
    const void* blkw, const void* blkb,
    const void* qw, const void* qb, const void* kw, const void* kb,
    const void* vw, const void* vb, const void* pw, const void* pb,
    void* out, float* Gpart, float* Gg,
    unsigned* aflag, unsigned* cflag,
    float* smem, int blk, int t)
{
    float (*sH)[SHP] = (float(*)[SHP])(smem + O_SH);
    float (*W1)[SHP] = (float(*)[SHP])(smem + O_B1);
    float (*W2)[SHP] = (float(*)[SHP])(smem + O_B2);
    float (*B3)[SHP] = (float(*)[SHP])(smem + O_B3);
    float (*W4)[SHP] = (float(*)[SHP])(smem + O_B4);
    float (*W5)[SHP] = (float(*)[SHP])(smem + O_B5);
    float* PS  = smem + O_B3;           // packed-partial half 0 (aliases B3)
    float* PS2 = smem + O_PS2;          // packed-partial half 1
    float* RED = smem + O_B3;           // combine reduction [16][20]
    float* sS  = smem + O_SS;
    float* suS = smem + O_SU;
    float* bkS = smem + O_BK;
    float* bqS = smem + O_BQ;
    float* bvS = smem + O_BV;
    float* beS = smem + O_BE;
    float* qkS = smem + O_QK;
    float* kqS = smem + O_KQ;
    float* qbkS = smem + O_QBK;
    float (*red)[DD] = (float(*)[DD])(smem + O_RED);

    const int row0 = blk * RPB;
    const int bb = blk >> 7;                          // batch of this block
    // lift/apply mapping: one row per thread
    const int ar = t >> 4, ac4 = (t & 15) << 2;
    // partial mapping: 16x16 grid of 4x4 tiles, two row-halves
    const int half = t >> 8, tt = t & 255;
    const int i4 = tt >> 4, j4 = tt & 15;
    const int r0 = i4 << 2, c0 = j4 << 2;
    // matmul mapping: 16x32 grid of 4x2 tiles
    const int er0 = (t >> 5) << 2, ec0 = (t & 31) << 1;
    // transpose mapping
    const int Ltr = t & 63, gtr = t >> 6;

    // ---- lift: 32 rows of h into resident LDS (1 row/thread) ----
    {
        const int gr = row0 + ar;
        float x0 = Acc<T>::ld(x, gr * 3 + 0);
        float x1 = Acc<T>::ld(x, gr * 3 + 1);
        float x2 = Acc<T>::ld(x, gr * 3 + 2);
        float o[4];
        #pragma unroll
        for (int b = 0; b < 4; b++) {
            int c = ac4 + b;
            o[b] = Acc<T>::ld(lb, c) + x0 * Acc<T>::ld(lw, c)
                 + x1 * Acc<T>::ld(lw, DD + c) + x2 * Acc<T>::ld(lw, 2 * DD + c);
        }
        *(float4*)&sH[ar][ac4] = make_float4(o[0], o[1], o[2], o[3]);
    }
    __syncthreads();

    for (int layer = 0; layer < NLAYER; layer++) {
        const unsigned ep = (unsigned)(layer + 1);
        float* GgL = Gg + (size_t)(layer * NB + bb) * PSZ;
        const int wOff = layer * DD * DD, bOff = layer * DD;

        // ---- A: packed symmetric G-partial, rows split across halves ----
        {
            if (i4 <= j4) {
                float m[4][4];
                #pragma unroll
                for (int a = 0; a < 4; a++)
                    #pragma unroll
                    for (int b = 0; b < 4; b++) m[a][b] = 0.f;
                const int nb = half * 16;
                #pragma unroll 8
                for (int n = nb; n < nb + 16; n++)
                    outer4x4(m, *(const float4*)&sH[n][r0], *(const float4*)&sH[n][c0]);
                float* dst = (half ? PS2 : PS) + (i4 * (33 - i4) / 2 + (j4 - i4)) * 16;
                #pragma unroll
                for (int a = 0; a < 4; a++)
                    #pragma unroll
                    for (int b = 0; b < 4; b++) dst[a * 4 + b] = m[a][b];
            }
            if (t < 2 * DD) {
                const int col = t & 63, hf = t >> 6;
                float* dst = hf ? PS2 : PS;
                float ss = 0.f;
                const int nb = hf * 16;
                #pragma unroll 8
                for (int n = nb; n < nb + 16; n++) ss += sH[n][col];
                dst[2176 + col] = ss;
                dst[2240 + col] = 0.f;      // pad (combine reduces it blindly)
            }
        }
        __syncthreads();
        // ---- B: sum halves, wave-linear coherent copy -> own Gpart slot ----
        {
            float* slot = Gpart + (size_t)blk * PSZ;
            #pragma unroll
            for (int k2 = 0; k2 < 2; k2++) {
                const int idx = 2 * (t + k2 * NT);
                stc2(&slot[idx], PS[idx] + PS2[idx], PS[idx + 1] + PS2[idx + 1]);
            }
            if (t < 128) {
                const int idx = 2 * (t + 2 * NT);
                stc2(&slot[idx], PS[idx] + PS2[idx], PS[idx + 1] + PS2[idx + 1]);
            }
        }
        __syncthreads();            // stc2 drained: partial fully visible
        if (t == 0) stw(&aflag[blk], ep);

        // ---- C: stage Wq/Wk + bias vectors (loads hide under aflag wait) ----
        if constexpr (sizeof(T) == 4) {
            const float* qwf = (const float*)qw + wOff;
            const float* kwf = (const float*)kw + wOff;
            #pragma unroll
            for (int k = 0; k < 2; k++) {
                const int i2 = 4 * (t + k * NT);
                *(float4*)&W1[i2 >> 6][i2 & 63] = *(const float4*)(qwf + i2);
                *(float4*)&W4[i2 >> 6][i2 & 63] = *(const float4*)(kwf + i2);
            }
        } else {
            const unsigned* q32 = (const unsigned*)qw + (wOff >> 1);
            const unsigned* k32 = (const unsigned*)kw + (wOff >> 1);
            #pragma unroll
            for (int k = 0; k < 4; k++) {
                const int i2 = t + k * NT;
                unsigned uq = q32[i2], uk = k32[i2];
                *(float2*)&W1[(2 * i2) >> 6][(2 * i2) & 63] = make_float2(bfu(uq & 0xffffu), bfu(uq >> 16));
                *(float2*)&W4[(2 * i2) >> 6][(2 * i2) & 63] = make_float2(bfu(uk & 0xffffu), bfu(uk >> 16));
            }
        }
        if (t < DD) {
            bkS[t] = Acc<T>::ld(kb, bOff + t);
            bqS[t] = Acc<T>::ld(qb, bOff + t);
            bvS[t] = Acc<T>::ld(vb, bOff + t);
        }

        // ---- D: wait partials; combine own chunk across 128 slots ----
        {
            if (t < NCH) pollw(&aflag[bb * NCH + t], ep);
            __syncthreads();            // C staging writes also ordered here
            const int chunk = blk & (NCH - 1);
            if (t < 144) {
                const int g = t / 9, p2 = t % 9;    // 16 slot-groups x 9 pairs
                const float* base = Gpart + (size_t)(bb * NCH + g * 8) * PSZ
                                  + chunk * CHW + 2 * p2;
                float ax = 0.f, ay = 0.f;
                #pragma unroll
                for (int s2 = 0; s2 < 8; s2++) {
                    float2 v = ldc2(base + (size_t)s2 * PSZ);
                    ax += v.x; ay += v.y;
                }
                RED[g * 20 + 2 * p2]     = ax;
                RED[g * 20 + 2 * p2 + 1] = ay;
            }
            __syncthreads();
            if (t < 9) {
                float s0 = 0.f, s1 = 0.f;
                #pragma unroll
                for (int g = 0; g < 16; g++) {
                    s0 += RED[g * 20 + 2 * t];
                    s1 += RED[g * 20 + 2 * t + 1];
                }
                stc2(&GgL[chunk * CHW + 2 * t], s0, s1);
            }
            __syncthreads();            // Gg stores drained
            if (t == 0) stw(&cflag[blk], ep);
        }

        // ---- diagonal transpose Wk -> W5 (2-way both sides = free) ----
        #pragma unroll
        for (int k = 0; k < 8; k++) {
            const int i = (Ltr + gtr + 8 * k) & 63;
            W5[i][Ltr] = W4[Ltr][i];
        }
        __syncthreads();            // W5 = Wk^T

        // ---- E (cflag shadow): A = Wq@WkT (NN, 4x2), qk, kq, qbk ----
        {
            float acc[4][2];
            #pragma unroll
            for (int a = 0; a < 4; a++) { acc[a][0] = 0.f; acc[a][1] = 0.f; }
            #pragma unroll 2
            for (int e = 0; e < DD; e += 4)
                mm4x2(acc,
                      *(const float4*)&W1[er0 + 0][e], *(const float4*)&W1[er0 + 1][e],
                      *(const float4*)&W1[er0 + 2][e], *(const float4*)&W1[er0 + 3][e],
                      *(const float2*)&W5[e + 0][ec0], *(const float2*)&W5[e + 1][ec0],
                      *(const float2*)&W5[e + 2][ec0], *(const float2*)&W5[e + 3][ec0]);
            #pragma unroll
            for (int a = 0; a < 4; a++)
                *(float2*)&W2[er0 + a][ec0] = make_float2(acc[a][0], acc[a][1]);

            if (t < DD) {               // qk = Wq@bk
                float u = 0.f;
                for (int e = 0; e < DD; e++) u += W1[t][e] * bkS[e];
                qkS[t] = u;
            } else if (t < 2 * DD) {    // kq = Wk@bq
                const int rr = t - DD;
                float u = 0.f;
                for (int e = 0; e < DD; e++) u += W4[rr][e] * bqS[e];
                kqS[rr] = u;
            } else if (t == 2 * DD) {   // qbk = bq.bk
                float u = 0.f;
                for (int e = 0; e < DD; e++) u += bqS[e] * bkS[e];
                qbkS[0] = u;
            }
        }
        __syncthreads();            // A done; W1/W4 free

        // ---- stage Wv -> W1, Wb -> W4 (hidden under cflag window) ----
        if constexpr (sizeof(T) == 4) {
            const float* vwf = (const float*)vw + wOff;
            const float* bwf = (const float*)blkw + wOff;
            #pragma unroll
            for (int k = 0; k < 2; k++) {
                const int i2 = 4 * (t + k * NT);
                *(float4*)&W1[i2 >> 6][i2 & 63] = *(const float4*)(vwf + i2);
                *(float4*)&W4[i2 >> 6][i2 & 63] = *(const float4*)(bwf + i2);
            }
        } else {
            const unsigned* v32 = (const unsigned*)vw + (wOff >> 1);
            const unsigned* b32 = (const unsigned*)blkw + (wOff >> 1);
            #pragma unroll
            for (int k = 0; k < 4; k++) {
                const int i2 = t + k * NT;
                unsigned uv = v32[i2], ub = b32[i2];
                *(float2*)&W1[(2 * i2) >> 6][(2 * i2) & 63] = make_float2(bfu(uv & 0xffffu), bfu(uv >> 16));
                *(float2*)&W4[(2 * i2) >> 6][(2 * i2) & 63] = make_float2(bfu(ub & 0xffffu), bfu(ub >> 16));
            }
        }

        // ---- F: wait all 128 chunks; stage G -> B3 (mirrored) + sS ----
        {
            if (t < NCH) pollw(&cflag[bb * NCH + t], ep);
            __syncthreads();            // G visible; Wv/Wb staging ordered
            if (t < 256) {
                if (i4 <= j4) {
                    const float* src = GgL + (i4 * (33 - i4) / 2 + (j4 - i4)) * 16;
                    #pragma unroll
                    for (int a = 0; a < 4; a++)
                        *(float4*)&B3[r0 + a][c0] = *(const float4*)&src[a * 4];
                } else {
                    const float* src = GgL + (j4 * (33 - j4) / 2 + (i4 - j4)) * 16;
                    #pragma unroll
                    for (int a = 0; a < 4; a++)
                        #pragma unroll
                        for (int b = 0; b < 4; b++)
                            B3[r0 + a][c0 + b] = src[b * 4 + a];
                }
            } else if (t < 256 + DD) {
                sS[t - 256] = GgL[2176 + (t - 256)];
            }
            __syncthreads();
        }

        // ---- G: W5 = T' = G@Wv + s bv^T (4x2) ; red = su partials ----
        {
            float acc[4][2];
            #pragma unroll
            for (int a = 0; a < 4; a++) {
                acc[a][0] = sS[er0 + a] * bvS[ec0 + 0];
                acc[a][1] = sS[er0 + a] * bvS[ec0 + 1];
            }
            #pragma unroll 2
            for (int e = 0; e < DD; e += 4)
                mm4x2(acc,
                      *(const float4*)&B3[er0 + 0][e], *(const float4*)&B3[er0 + 1][e],
                      *(const float4*)&B3[er0 + 2][e], *(const float4*)&B3[er0 + 3][e],
                      *(const float2*)&W1[e + 0][ec0], *(const float2*)&W1[e + 1][ec0],
                      *(const float2*)&W1[e + 2][ec0], *(const float2*)&W1[e + 3][ec0]);
            #pragma unroll
            for (int a = 0; a < 4; a++)
                *(float2*)&W5[er0 + a][ec0] = make_float2(acc[a][0], acc[a][1]);
        }
        {   // su[c] partials: 8 k-groups x 64 cols
            const int c = t & 63, q = t >> 6;
            float u = 0.f;
            #pragma unroll
            for (int d2 = 0; d2 < 8; d2++) u += sS[q * 8 + d2] * W1[q * 8 + d2][c];
            red[q][c] = u;
        }
        __syncthreads();
        if (t < DD) {
            float u = 0.f;
            #pragma unroll
            for (int g = 0; g < 8; g++) u += red[g][t];
            suS[t] = u + (float)NN * bvS[t];
        }
        __syncthreads();

        // ---- H: weff = Wb + C0*(A@T' + qk su^T) -> B3 ; beff ----
        {
            float acc[4][2];
            #pragma unroll
            for (int a = 0; a < 4; a++) {
                acc[a][0] = qkS[er0 + a] * suS[ec0 + 0];
                acc[a][1] = qkS[er0 + a] * suS[ec0 + 1];
            }
            #pragma unroll 2
            for (int e = 0; e < DD; e += 4)
                mm4x2(acc,
                      *(const float4*)&W2[er0 + 0][e], *(const float4*)&W2[er0 + 1][e],
                      *(const float4*)&W2[er0 + 2][e], *(const float4*)&W2[er0 + 3][e],
                      *(const float2*)&W5[e + 0][ec0], *(const float2*)&W5[e + 1][ec0],
                      *(const float2*)&W5[e + 2][ec0], *(const float2*)&W5[e + 3][ec0]);
            float wloc[4][2];
            #pragma unroll
            for (int a = 0; a < 4; a++) {
                wloc[a][0] = W4[er0 + a][ec0 + 0] + C0F * acc[a][0];
                wloc[a][1] = W4[er0 + a][ec0 + 1] + C0F * acc[a][1];
            }
            {   // beff partials (reads W5 only)
                const int c = t & 63, q = t >> 6;
                float u = 0.f;
                #pragma unroll
                for (int e2 = 0; e2 < 8; e2++) u += kqS[q * 8 + e2] * W5[q * 8 + e2][c];
                red[q][c] = u;
            }
            __syncthreads();            // red visible; B3 (G) reads done
            #pragma unroll
            for (int a = 0; a < 4; a++)
                *(float2*)&B3[er0 + a][ec0] = make_float2(wloc[a][0], wloc[a][1]);
            if (t < DD) {
                float u = 0.f;
                #pragma unroll
                for (int g = 0; g < 8; g++) u += red[g][t];
                beS[t] = Acc<T>::ld(blkb, bOff + t) + C0F * (u + qbkS[0] * suS[t]);
            }
        }
        __syncthreads();

        // ---- apply: h' = gelu(h@weff + beff), 1 row/thread ----
        float o[4];
        {
            float acc2[4];
            #pragma unroll
            for (int b = 0; b < 4; b++) acc2[b] = beS[ac4 + b];
            for (int d = 0; d < DD; d++) {
                float hv = sH[ar][d];
                float4 w4 = *(const float4*)&B3[d][ac4];
                acc2[0] += hv * w4.x; acc2[1] += hv * w4.y;
                acc2[2] += hv * w4.z; acc2[3] += hv * w4.w;
            }
            #pragma unroll
            for (int b = 0; b < 4; b++) o[b] = gelu_exact(acc2[b]);
        }

        if (layer == NLAYER - 1) {
            float pbv = Acc<T>::ld(pb, 0);
            float p = 0.f;
            #pragma unroll
            for (int b = 0; b < 4; b++) p += o[b] * Acc<T>::ld(pw, ac4 + b);
            p += __shfl_xor(p, 1);
            p += __shfl_xor(p, 2);
            p += __shfl_xor(p, 4);
            p += __shfl_xor(p, 8);
            if ((t & 15) == 0) Acc<T>::st(out, row0 + ar, p + pbv);
        } else {
            __syncthreads();    // weff/beS/sH reads done before sH overwrite
            *(float4*)&sH[ar][ac4] = make_float4(o[0], o[1], o[2], o[3]);
            __syncthreads();
        }
    }
}

__global__ __launch_bounds__(NT, 1) void gno_kernel(
    const void* x, const void* lw, const void* lb,
    const void* blkw, const void* blkb,
    const void* qw, const void* qb, const void* kw, const void* kb,
    const void* vw, const void* vb, const void* pw, const void* pb,
    void* out, float* Gpart, float* Gg, unsigned* bar, int mode)
{
    __shared__ alignas(16) float smem[SM_TOT];   // 109312 B
    __shared__ int stot;

    const int blk = blockIdx.x, t = threadIdx.x;

    bool isbf;
    if (mode >= 0) {
        isbf = (mode == 1);
    } else {
        // fallback: device dtype scan (same result in every block)
        if (t == 0) stot = 0;
        __syncthreads();
        int cdt = 0;
        const unsigned int* xw = (const unsigned int*)x;
        for (int i = t; i < 8192; i += NT) {
            unsigned u = xw[i] & 0xFFFFu;
            int e = (u >> 7) & 0xFF;
            cdt += (u == 0u || (e >= 100 && e <= 142)) ? 1 : 0;
        }
        atomicAdd(&stot, cdt);
        __syncthreads();
        isbf = (stot > 4915);
    }

    unsigned* aflag = bar;          // [256] producer epochs
    unsigned* cflag = bar + 256;    // [256] combine epochs

    if (isbf)
        run_net<bf16>(x, lw, lb, blkw, blkb, qw, qb, kw, kb, vw, vb, pw, pb,
                      out, Gpart, Gg, aflag, cflag, smem, blk, t);
    else
        run_net<float>(x, lw, lb, blkw, blkb, qw, qb, kw, kb, vw, vb, pw, pb,
                       out, Gpart, Gg, aflag, cflag, smem, blk, t);
}

extern "C" void kernel_launch(void* const* d_in, const int* in_sizes, int n_in,
                              void* d_out, int out_size, void* d_ws, size_t ws_size,
                              hipStream_t stream)
{
    const void* x    = d_in[0];
    const void* lw   = d_in[1];
    const void* lb   = d_in[2];
    const void* blkw = d_in[3];
    const void* blkb = d_in[4];
    const void* qw   = d_in[5];
    const void* qb   = d_in[6];
    const void* kw   = d_in[7];
    const void* kb   = d_in[8];
    const void* vw   = d_in[9];
    const void* vb   = d_in[10];
    const void* pw   = d_in[11];
    const void* pb   = d_in[12];

    // x = [2,64,64,3]: fp32 -> 98304 B, bf16 -> 49152 B
    int mode = -1;
    if (in_sizes && n_in > 0) {
        if (in_sizes[0] == 49152) mode = 1;
        else if (in_sizes[0] == 98304) mode = 0;
    }

    unsigned* bar = (unsigned*)d_ws;                      // [512] flag words
    float* Gpart  = (float*)d_ws + 512;                   // [256][2304] 2.36 MB
    float* Gg     = Gpart + (size_t)NBLK * PSZ;           // [4][2][2304] per-layer

    hipMemsetAsync(bar, 0, 512 * sizeof(unsigned), stream);
    gno_kernel<<<NBLK, NT, 0, stream>>>(x, lw, lb, blkw, blkb, qw, qb, kw, kb,
                                        vw, vb, pw, pb, d_out, Gpart, Gg, bar, mode);
}

// Round 9
// 177.603 us; speedup vs baseline: 1.8369x; 1.8369x over previous
//
#include <hip/hip_runtime.h>
#include <hip/hip_bf16.h>
#include <math.h>

// GNO collapsed: h = lift(x); per layer h = gelu(h@weff + beff).
// Round 21 (= round 20 with compile fix: dead W5-alias removed).
// r15 champion base (NT=256, 2 polls/layer, packed symmetric partials,
// proven 92us) + h-side algebra swap:
//   h@weff = HWB + c0*(HA@T' + hqk su^T),  beff -> vrow,
//   HQ = h@Wq, HA = HQ@Wk^T, HWB = h@Wb, hqk = HQ@bk   (all G-INDEPENDENT,
//   computed in the flag-propagation shadows). Post-G serial path is now
//   T'(262K MAC) + FINAL(131K) -- the old H phase (262K, and its 3.4M
//   bank conflicts) is deleted from the critical path.
// r16-r19 lessons: NT=512 family generates ~550MB scratch traffic (dead end);
// unpadded LDS causes 4-way row conflicts (dead end); conflicts in shadow
// phases are ~1us (ignore). Fabric unchanged from r15.

#define NLAYER 4
#define NB 2
#define NN 4096
#define DD 64
#define RPB 32              // rows per block (8192 rows / 256 blocks)
#define NT 256
#define NBLK 256
#define SHP 68              // padded LDS row stride (floats)
#define C0F (1.0f/32768.0f)
#define PSZ 2304            // packed partial floats: 2176 tri + 64 s + 64 pad
#define NCH 128             // combine chunks per batch
#define CHW 18              // floats per combine chunk

typedef __hip_bfloat16 bf16;
typedef unsigned long long u64t;

// ---- LDS float offsets ----
#define O_SH   0            // sH  [32][68] resident h rows
#define O_HQ   2176         // HQ  [32][68] h@Wq
#define O_HA   4352         // HA  [32][68] HQ@Wk^T
#define O_HWB  6528         // HWB [32][68] h@Wb
#define O_W1   8704         // W1  [64][68] Wq -> Wv
#define O_W4   13056        // W4  [64][68] Wk -> Wb
#define O_W5   17408        // W5  [64][68] WkT -> T'
#define O_B3   21760        // B3  [64][68] PS/RED alias; G
#define O_SS   26112
#define O_SU   26176
#define O_BK   26240
#define O_BQ   26304
#define O_BV   26368
#define O_VR   26432        // vrow [64]
#define O_KQ   26496        // kq [64]
#define O_HK   26560        // hqk [32]
#define O_QBK  26624        // [4]
#define O_RED  26640        // red  [4][64]
#define O_RED2 26896        // red2 [4][64]
#define SM_TOT 27152        // 108608 B -> 1 block/CU

__device__ __forceinline__ float b2f(const bf16 v) { return __bfloat162float(v); }

template <typename T> struct Acc;
template <> struct Acc<float> {
    static __device__ __forceinline__ float ld(const void* p, int i) { return ((const float*)p)[i]; }
    static __device__ __forceinline__ void st(void* p, int i, float v) { ((float*)p)[i] = v; }
};
template <> struct Acc<bf16> {
    static __device__ __forceinline__ float ld(const void* p, int i) { return b2f(((const bf16*)p)[i]); }
    static __device__ __forceinline__ void st(void* p, int i, float v) { ((bf16*)p)[i] = __float2bfloat16(v); }
};

__device__ __forceinline__ float gelu_exact(float x) {
    return 0.5f * x * (1.0f + erff(x * 0.70710678118654752f));
}

// ---- device-coherent helpers (agent scope, relaxed) ----
__device__ __forceinline__ float2 ldc2(const float* p) {
    u64t v = __hip_atomic_load((const u64t*)p, __ATOMIC_RELAXED, __HIP_MEMORY_SCOPE_AGENT);
    float2 r;
    r.x = __uint_as_float((unsigned)v);
    r.y = __uint_as_float((unsigned)(v >> 32));
    return r;
}
__device__ __forceinline__ void stc2(float* p, float a, float b) {
    u64t v = ((u64t)__float_as_uint(b) << 32) | (u64t)__float_as_uint(a);
    __hip_atomic_store((u64t*)p, v, __ATOMIC_RELAXED, __HIP_MEMORY_SCOPE_AGENT);
}
__device__ __forceinline__ unsigned ldw(unsigned* p) {
    return __hip_atomic_load(p, __ATOMIC_RELAXED, __HIP_MEMORY_SCOPE_AGENT);
}
__device__ __forceinline__ void stw(unsigned* p, unsigned v) {
    __hip_atomic_store(p, v, __ATOMIC_RELAXED, __HIP_MEMORY_SCOPE_AGENT);
}
__device__ __forceinline__ void pollw(unsigned* p, unsigned ep) {
    int guard = 0;
    while (ldw(p) < ep && ++guard < (1 << 18)) __builtin_amdgcn_s_sleep(2);
}

// acc[a][b] += sum_k L[a].k * R[k].b
__device__ __forceinline__ void mm4x4(float (&acc)[4][4],
    float4 L0, float4 L1, float4 L2, float4 L3,
    float4 R0, float4 R1, float4 R2, float4 R3)
{
    const float L[4][4] = {{L0.x,L0.y,L0.z,L0.w},{L1.x,L1.y,L1.z,L1.w},
                           {L2.x,L2.y,L2.z,L2.w},{L3.x,L3.y,L3.z,L3.w}};
    const float R[4][4] = {{R0.x,R0.y,R0.z,R0.w},{R1.x,R1.y,R1.z,R1.w},
                           {R2.x,R2.y,R2.z,R2.w},{R3.x,R3.y,R3.z,R3.w}};
    #pragma unroll
    for (int a = 0; a < 4; a++)
        #pragma unroll
        for (int k = 0; k < 4; k++)
            #pragma unroll
            for (int b = 0; b < 4; b++)
                acc[a][b] += L[a][k] * R[k][b];
}

// acc[a][b] += A.a * B.b
__device__ __forceinline__ void outer4x4(float (&acc)[4][4], float4 A, float4 B)
{
    const float Aa[4] = {A.x, A.y, A.z, A.w};
    const float Ba[4] = {B.x, B.y, B.z, B.w};
    #pragma unroll
    for (int a = 0; a < 4; a++)
        #pragma unroll
        for (int b = 0; b < 4; b++)
            acc[a][b] += Aa[a] * Ba[b];
}

template <typename T>
__device__ void run_net(
    const void* x, const void* lw, const void* lb,
    const void* blkw, const void* blkb,
    const void* qw, const void* qb, const void* kw, const void* kb,
    const void* vw, const void* vb, const void* pw, const void* pb,
    void* out, float* Gpart, float* Gg,
    unsigned* aflag, unsigned* cflag,
    float* smem, int blk, int t)
{
    float (*sH)[SHP]  = (float(*)[SHP])(smem + O_SH);
    float (*HQ)[SHP]  = (float(*)[SHP])(smem + O_HQ);
    float (*HA)[SHP]  = (float(*)[SHP])(smem + O_HA);
    float (*HWB)[SHP] = (float(*)[SHP])(smem + O_HWB);
    float (*W1)[SHP]  = (float(*)[SHP])(smem + O_W1);
    float (*W4)[SHP]  = (float(*)[SHP])(smem + O_W4);
    float (*W5r)[SHP] = (float(*)[SHP])(smem + O_W5);
    float (*B3)[SHP]  = (float(*)[SHP])(smem + O_B3);
    float* PS  = smem + O_B3;           // packed-partial scratch (aliases B3)
    float* RED = smem + O_B3;           // combine reduction [16][20]
    float* sS  = smem + O_SS;
    float* suS = smem + O_SU;
    float* bkS = smem + O_BK;
    float* bqS = smem + O_BQ;
    float* bvS = smem + O_BV;
    float* vrS = smem + O_VR;
    float* kqS = smem + O_KQ;
    float* hkS = smem + O_HK;
    float* qbkS = smem + O_QBK;
    float (*red)[DD]  = (float(*)[DD])(smem + O_RED);
    float (*red2)[DD] = (float(*)[DD])(smem + O_RED2);

    const int row0 = blk * RPB;
    const int bb = blk >> 7;                      // batch of this block
    const int r = t >> 4, c4 = (t & 15) << 2;     // row-pair mapping
    const int i4 = t >> 4, j4 = t & 15;           // 4x4 tile grid coords
    const int r0 = i4 << 2, c0 = j4 << 2;
    const int Ltr = t & 63, gtr = t >> 6;         // transpose mapping

    // ---- lift: 32 rows of h into resident LDS ----
    #pragma unroll
    for (int a = 0; a < 2; a++) {
        const int row = r + 16 * a, gr = row0 + row;
        float x0 = Acc<T>::ld(x, gr * 3 + 0);
        float x1 = Acc<T>::ld(x, gr * 3 + 1);
        float x2 = Acc<T>::ld(x, gr * 3 + 2);
        float o[4];
        #pragma unroll
        for (int b = 0; b < 4; b++) {
            int c = c4 + b;
            o[b] = Acc<T>::ld(lb, c) + x0 * Acc<T>::ld(lw, c)
                 + x1 * Acc<T>::ld(lw, DD + c) + x2 * Acc<T>::ld(lw, 2 * DD + c);
        }
        *(float4*)&sH[row][c4] = make_float4(o[0], o[1], o[2], o[3]);
    }
    __syncthreads();

    for (int layer = 0; layer < NLAYER; layer++) {
        const unsigned ep = (unsigned)(layer + 1);
        float* GgL = Gg + (size_t)(layer * NB + bb) * PSZ;
        const int wOff = layer * DD * DD, bOff = layer * DD;

        // ---- A: packed symmetric G-partial (upper triangle) into PS ----
        {
            if (i4 <= j4) {
                float m[4][4];
                #pragma unroll
                for (int a = 0; a < 4; a++)
                    #pragma unroll
                    for (int b = 0; b < 4; b++) m[a][b] = 0.f;
                #pragma unroll 8
                for (int n = 0; n < RPB; n++)
                    outer4x4(m, *(const float4*)&sH[n][r0], *(const float4*)&sH[n][c0]);
                float* dst = PS + (i4 * (33 - i4) / 2 + (j4 - i4)) * 16;
                #pragma unroll
                for (int a = 0; a < 4; a++)
                    #pragma unroll
                    for (int b = 0; b < 4; b++) dst[a * 4 + b] = m[a][b];
            }
            if (t < DD) {
                float ss = 0.f;
                #pragma unroll 8
                for (int n = 0; n < RPB; n++) ss += sH[n][t];
                PS[2176 + t] = ss;
                PS[2240 + t] = 0.f;     // pad (combine reduces it blindly)
            }
        }
        __syncthreads();
        // ---- B: wave-linear coherent copy PS -> own Gpart slot ----
        {
            float* slot = Gpart + (size_t)blk * PSZ;
            #pragma unroll
            for (int k2 = 0; k2 < 4; k2++) {
                const int idx = 2 * (t + k2 * NT);
                stc2(&slot[idx], PS[idx], PS[idx + 1]);
            }
            if (t < 128) {
                const int idx = 2 * (t + 4 * NT);
                stc2(&slot[idx], PS[idx], PS[idx + 1]);
            }
        }
        __syncthreads();            // stc2 drained: partial fully visible
        if (t == 0) stw(&aflag[blk], ep);

        // ---- C (aflag shadow): stage Wq->W1, Wk->W4, bias vectors ----
        for (int i2 = t; i2 < DD * DD; i2 += NT) {
            W1[i2 >> 6][i2 & 63] = Acc<T>::ld(qw, wOff + i2);
            W4[i2 >> 6][i2 & 63] = Acc<T>::ld(kw, wOff + i2);
        }
        if (t < DD) {
            bkS[t] = Acc<T>::ld(kb, bOff + t);
            bqS[t] = Acc<T>::ld(qb, bOff + t);
            bvS[t] = Acc<T>::ld(vb, bOff + t);
        }

        // ---- D: wait partials; combine own chunk across 128 slots ----
        {
            if (t < NCH) pollw(&aflag[bb * NCH + t], ep);
            __syncthreads();            // C staging writes ordered
            const int chunk = blk & (NCH - 1);
            if (t < 144) {
                const int g = t / 9, p2 = t % 9;    // 16 slot-groups x 9 pairs
                const float* base = Gpart + (size_t)(bb * NCH + g * 8) * PSZ
                                  + chunk * CHW + 2 * p2;
                float ax = 0.f, ay = 0.f;
                #pragma unroll
                for (int s2 = 0; s2 < 8; s2++) {
                    float2 v = ldc2(base + (size_t)s2 * PSZ);
                    ax += v.x; ay += v.y;
                }
                RED[g * 20 + 2 * p2]     = ax;
                RED[g * 20 + 2 * p2 + 1] = ay;
            }
            __syncthreads();
            if (t < 9) {
                float s0 = 0.f, s1 = 0.f;
                #pragma unroll
                for (int g = 0; g < 16; g++) {
                    s0 += RED[g * 20 + 2 * t];
                    s1 += RED[g * 20 + 2 * t + 1];
                }
                stc2(&GgL[chunk * CHW + 2 * t], s0, s1);
            }
            __syncthreads();            // Gg stores drained
            if (t == 0) stw(&cflag[blk], ep);
        }

        // ---- E region A (cflag shadow): W5 = Wk^T (diag), HQ = h@Wq,
        //      kq = Wk@bq, qbk = bq.bk ----
        #pragma unroll
        for (int k = 0; k < 16; k++) {
            const int i = (Ltr + gtr + 4 * k) & 63;
            W5r[i][Ltr] = W4[Ltr][i];
        }
        #pragma unroll
        for (int a = 0; a < 2; a++) {
            const int row = r + 16 * a;
            float acc[4] = {0.f, 0.f, 0.f, 0.f};
            for (int d = 0; d < DD; d++) {
                const float hv = sH[row][d];
                const float4 w4v = *(const float4*)&W1[d][c4];
                acc[0] += hv * w4v.x; acc[1] += hv * w4v.y;
                acc[2] += hv * w4v.z; acc[3] += hv * w4v.w;
            }
            *(float4*)&HQ[row][c4] = make_float4(acc[0], acc[1], acc[2], acc[3]);
        }
        if (t < DD) {               // kq = Wk@bq
            float u = 0.f;
            for (int e = 0; e < DD; e++) u += W4[t][e] * bqS[e];
            kqS[t] = u;
        } else if (t == DD) {       // qbk = bq.bk
            float u = 0.f;
            for (int e = 0; e < DD; e++) u += bqS[e] * bkS[e];
            qbkS[0] = u;
        }
        __syncthreads();            // W5=WkT, HQ, kq, qbk ready

        // ---- E region B: HA = HQ@WkT, hqk = HQ@bk; stage Wv->W1, Wb->W4 ----
        #pragma unroll
        for (int a = 0; a < 2; a++) {
            const int row = r + 16 * a;
            float acc[4] = {0.f, 0.f, 0.f, 0.f};
            for (int d = 0; d < DD; d++) {
                const float hv = HQ[row][d];
                const float4 w4v = *(const float4*)&W5r[d][c4];
                acc[0] += hv * w4v.x; acc[1] += hv * w4v.y;
                acc[2] += hv * w4v.z; acc[3] += hv * w4v.w;
            }
            *(float4*)&HA[row][c4] = make_float4(acc[0], acc[1], acc[2], acc[3]);
        }
        if (t < RPB) {              // hqk = HQ@bk
            float u = 0.f;
            for (int e = 0; e < DD; e++) u += HQ[t][e] * bkS[e];
            hkS[t] = u;
        }
        for (int i2 = t; i2 < DD * DD; i2 += NT) {
            W1[i2 >> 6][i2 & 63] = Acc<T>::ld(vw, wOff + i2);
            W4[i2 >> 6][i2 & 63] = Acc<T>::ld(blkw, wOff + i2);
        }
        __syncthreads();            // HA, hqk, Wv, Wb ready

        // ---- E region C: HWB = h@Wb ----
        #pragma unroll
        for (int a = 0; a < 2; a++) {
            const int row = r + 16 * a;
            float acc[4] = {0.f, 0.f, 0.f, 0.f};
            for (int d = 0; d < DD; d++) {
                const float hv = sH[row][d];
                const float4 w4v = *(const float4*)&W4[d][c4];
                acc[0] += hv * w4v.x; acc[1] += hv * w4v.y;
                acc[2] += hv * w4v.z; acc[3] += hv * w4v.w;
            }
            *(float4*)&HWB[row][c4] = make_float4(acc[0], acc[1], acc[2], acc[3]);
        }

        // ---- F: wait all 128 chunks; stage G -> B3 (mirrored) + sS ----
        {
            if (t < NCH) pollw(&cflag[bb * NCH + t], ep);
            __syncthreads();            // G visible; HWB writes ordered
            if (i4 <= j4) {
                const float* src = GgL + (i4 * (33 - i4) / 2 + (j4 - i4)) * 16;
                #pragma unroll
                for (int a = 0; a < 4; a++)
                    *(float4*)&B3[r0 + a][c0] = *(const float4*)&src[a * 4];
            } else {
                const float* src = GgL + (j4 * (33 - j4) / 2 + (i4 - j4)) * 16;
                #pragma unroll
                for (int a = 0; a < 4; a++)
                    #pragma unroll
                    for (int b = 0; b < 4; b++)
                        B3[r0 + a][c0 + b] = src[b * 4 + a];
            }
            if (t < DD) sS[t] = GgL[2176 + t];
            __syncthreads();
        }

        // ---- G: W5 = T' = G@Wv + s bv^T ; red = su partials ----
        {
            float acc[4][4];
            #pragma unroll
            for (int a = 0; a < 4; a++)
                #pragma unroll
                for (int b = 0; b < 4; b++) acc[a][b] = sS[r0 + a] * bvS[c0 + b];
            #pragma unroll 2
            for (int e = 0; e < DD; e += 4)
                mm4x4(acc,
                      *(const float4*)&B3[r0 + 0][e], *(const float4*)&B3[r0 + 1][e],
                      *(const float4*)&B3[r0 + 2][e], *(const float4*)&B3[r0 + 3][e],
                      *(const float4*)&W1[e + 0][c0], *(const float4*)&W1[e + 1][c0],
                      *(const float4*)&W1[e + 2][c0], *(const float4*)&W1[e + 3][c0]);
            #pragma unroll
            for (int a = 0; a < 4; a++)
                *(float4*)&W5r[r0 + a][c0] = make_float4(acc[a][0], acc[a][1], acc[a][2], acc[a][3]);
        }
        {   // su[c] = sum_d s[d]*Wv[d][c] partials
            const int c = t & 63, q = t >> 6;
            float u = 0.f;
            #pragma unroll
            for (int d2 = 0; d2 < 16; d2++) u += sS[q * 16 + d2] * W1[q * 16 + d2][c];
            red[q][c] = u;
        }
        __syncthreads();            // T' ready
        // ---- su final + vrow partials (red2 = kq.T') ----
        if (t < DD) suS[t] = red[0][t] + red[1][t] + red[2][t] + red[3][t] + (float)NN * bvS[t];
        {
            const int c = t & 63, q = t >> 6;
            float u = 0.f;
            #pragma unroll
            for (int e2 = 0; e2 < 16; e2++) u += kqS[q * 16 + e2] * W5r[q * 16 + e2][c];
            red2[q][c] = u;
        }
        __syncthreads();
        if (t < DD) vrS[t] = Acc<T>::ld(blkb, bOff + t)
                           + C0F * (red2[0][t] + red2[1][t] + red2[2][t] + red2[3][t]
                                    + qbkS[0] * suS[t]);
        __syncthreads();

        // ---- FINAL: h' = gelu(HWB + c0*(HA@T' + hqk su^T) + vrow) ----
        float o[2][4];
        #pragma unroll
        for (int a = 0; a < 2; a++) {
            const int row = r + 16 * a;
            float acc2[4] = {0.f, 0.f, 0.f, 0.f};
            for (int d = 0; d < DD; d++) {
                const float hv = HA[row][d];
                const float4 w4v = *(const float4*)&W5r[d][c4];
                acc2[0] += hv * w4v.x; acc2[1] += hv * w4v.y;
                acc2[2] += hv * w4v.z; acc2[3] += hv * w4v.w;
            }
            #pragma unroll
            for (int b = 0; b < 4; b++) {
                float val = HWB[row][c4 + b]
                          + C0F * (acc2[b] + hkS[row] * suS[c4 + b])
                          + vrS[c4 + b];
                o[a][b] = gelu_exact(val);
            }
        }

        if (layer == NLAYER - 1) {
            float pbv = Acc<T>::ld(pb, 0);
            #pragma unroll
            for (int a = 0; a < 2; a++) {
                float p = 0.f;
                #pragma unroll
                for (int b = 0; b < 4; b++) p += o[a][b] * Acc<T>::ld(pw, c4 + b);
                p += __shfl_xor(p, 1);
                p += __shfl_xor(p, 2);
                p += __shfl_xor(p, 4);
                p += __shfl_xor(p, 8);
                if ((t & 15) == 0) Acc<T>::st(out, row0 + r + 16 * a, p + pbv);
            }
        } else {
            // FINAL reads no sH -> safe to overwrite directly
            #pragma unroll
            for (int a = 0; a < 2; a++)
                *(float4*)&sH[r + 16 * a][c4] =
                    make_float4(o[a][0], o[a][1], o[a][2], o[a][3]);
            __syncthreads();
        }
    }
}

__global__ __launch_bounds__(NT, 1) void gno_kernel(
    const void* x, const void* lw, const void* lb,
    const void* blkw, const void* blkb,
    const void* qw, const void* qb, const void* kw, const void* kb,
    const void* vw, const void* vb, const void* pw, const void* pb,
    void* out, float* Gpart, float* Gg, unsigned* bar, int mode)
{
    __shared__ alignas(16) float smem[SM_TOT];   // 108608 B
    __shared__ int stot;

    const int blk = blockIdx.x, t = threadIdx.x;

    bool isbf;
    if (mode >= 0) {
        isbf = (mode == 1);
    } else {
        // fallback: device dtype scan (same result in every block)
        if (t == 0) stot = 0;
        __syncthreads();
        int cdt = 0;
        const unsigned int* xw = (const unsigned int*)x;
        for (int i = t; i < 8192; i += NT) {
            unsigned u = xw[i] & 0xFFFFu;
            int e = (u >> 7) & 0xFF;
            cdt += (u == 0u || (e >= 100 && e <= 142)) ? 1 : 0;
        }
        atomicAdd(&stot, cdt);
        __syncthreads();
        isbf = (stot > 4915);
    }

    unsigned* aflag = bar;          // [256] producer epochs
    unsigned* cflag = bar + 256;    // [256] combine epochs

    if (isbf)
        run_net<bf16>(x, lw, lb, blkw, blkb, qw, qb, kw, kb, vw, vb, pw, pb,
                      out, Gpart, Gg, aflag, cflag, smem, blk, t);
    else
        run_net<float>(x, lw, lb, blkw, blkb, qw, qb, kw, kb, vw, vb, pw, pb,
                       out, Gpart, Gg, aflag, cflag, smem, blk, t);
}

extern "C" void kernel_launch(void* const* d_in, const int* in_sizes, int n_in,
                              void* d_out, int out_size, void* d_ws, size_t ws_size,
                              hipStream_t stream)
{
    const void* x    = d_in[0];
    const void* lw   = d_in[1];
    const void* lb   = d_in[2];
    const void* blkw = d_in[3];
    const void* blkb = d_in[4];
    const void* qw   = d_in[5];
    const void* qb   = d_in[6];
    const void* kw   = d_in[7];
    const void* kb   = d_in[8];
    const void* vw   = d_in[9];
    const void* vb   = d_in[10];
    const void* pw   = d_in[11];
    const void* pb   = d_in[12];

    // x = [2,64,64,3]: fp32 -> 98304 B, bf16 -> 49152 B
    int mode = -1;
    if (in_sizes && n_in > 0) {
        if (in_sizes[0] == 49152) mode = 1;
        else if (in_sizes[0] == 98304) mode = 0;
    }

    unsigned* bar = (unsigned*)d_ws;                      // [512] flag words
    float* Gpart  = (float*)d_ws + 512;                   // [256][2304] 2.36 MB
    float* Gg     = Gpart + (size_t)NBLK * PSZ;           // [4][2][2304] per-layer

    (void)hipMemsetAsync(bar, 0, 512 * sizeof(unsigned), stream);
    gno_kernel<<<NBLK, NT, 0, stream>>>(x, lw, lb, blkw, blkb, qw, qb, kw, kb,
                                        vw, vb, pw, pb, d_out, Gpart, Gg, bar, mode);
}

// Round 10
// 157.330 us; speedup vs baseline: 2.0736x; 1.1289x over previous
//
#include <hip/hip_runtime.h>
#include <hip/hip_bf16.h>
#include <math.h>

// GNO collapsed: h = lift(x); per layer h = gelu(h@weff + beff),
//   weff = Wb + c0*(A@T' + qk su^T),  beff = bb + c0*(kq.T' + qbk su),
//   A = Wq@Wk^T, qk = Wq@bk, kq = Wk@bq, qbk = bq.bk     (G-INDEPENDENT)
//   T' = G@Wv + s bv^T,  su = Wv^T s + N bv,  G = h^T h, s = h^T 1,
//   c0 = (1/sqrt(64))/4096.
// Round 22: REVERT to the round-15 champion (92us dispatch / 159us bench).
// Session ledger: r16 (unpadded LDS + DMA) 103us; r17 (VGPR prefetch +
// transpose) 109us; r18/r19 (NT=512) 252us scratch-spill dead end; r20/r21
// (h-side algebra swap) 147us -- conflicts doubled, "shadow" work is serial
// under lockstep blocks. r15 is the verified local optimum: sync-fabric-
// bound (~20us/layer = 2 LLC round-trips + partial drain + 2 serial
// matmuls), VALUBusy 30%, HBM 3%.
// Structure: NT=256, 2 polls/layer, packed symmetric G-partials (2304 fl),
// wave-linear stc2 producer stores, all-block 18-float chunk combine,
// shadow-computed A/qk/kq/qbk between cflag-store and cflag-poll,
// host-side dtype detect, s_sleep(2) polls.

#define NLAYER 4
#define NB 2
#define NN 4096
#define DD 64
#define RPB 32              // rows per block (8192 rows / 256 blocks)
#define NT 256
#define NBLK 256
#define SHP 68              // padded LDS row stride (floats)
#define C0F (1.0f/32768.0f)
#define PSZ 2304            // packed partial floats: 2176 tri + 64 s + 64 pad
#define NCH 128             // combine chunks per batch (= producers per batch)
#define CHW 18              // floats per combine chunk (128*18 = 2304)

typedef __hip_bfloat16 bf16;
typedef unsigned long long u64t;

__device__ __forceinline__ float b2f(const bf16 v) { return __bfloat162float(v); }

template <typename T> struct Acc;
template <> struct Acc<float> {
    static __device__ __forceinline__ float ld(const void* p, int i) { return ((const float*)p)[i]; }
    static __device__ __forceinline__ void st(void* p, int i, float v) { ((float*)p)[i] = v; }
};
template <> struct Acc<bf16> {
    static __device__ __forceinline__ float ld(const void* p, int i) { return b2f(((const bf16*)p)[i]); }
    static __device__ __forceinline__ void st(void* p, int i, float v) { ((bf16*)p)[i] = __float2bfloat16(v); }
};

__device__ __forceinline__ float gelu_exact(float x) {
    return 0.5f * x * (1.0f + erff(x * 0.70710678118654752f));
}

// ---- device-coherent helpers (agent scope, relaxed) ----
__device__ __forceinline__ float2 ldc2(const float* p) {
    u64t v = __hip_atomic_load((const u64t*)p, __ATOMIC_RELAXED, __HIP_MEMORY_SCOPE_AGENT);
    float2 r;
    r.x = __uint_as_float((unsigned)v);
    r.y = __uint_as_float((unsigned)(v >> 32));
    return r;
}
__device__ __forceinline__ void stc2(float* p, float a, float b) {
    u64t v = ((u64t)__float_as_uint(b) << 32) | (u64t)__float_as_uint(a);
    __hip_atomic_store((u64t*)p, v, __ATOMIC_RELAXED, __HIP_MEMORY_SCOPE_AGENT);
}
__device__ __forceinline__ unsigned ldw(unsigned* p) {
    return __hip_atomic_load(p, __ATOMIC_RELAXED, __HIP_MEMORY_SCOPE_AGENT);
}
__device__ __forceinline__ void stw(unsigned* p, unsigned v) {
    __hip_atomic_store(p, v, __ATOMIC_RELAXED, __HIP_MEMORY_SCOPE_AGENT);
}
// Poll epoch word until >= ep. Producer's __syncthreads (vmcnt(0) per wave)
// precedes its flag store, so flag-visibility implies data-visibility.
__device__ __forceinline__ void pollw(unsigned* p, unsigned ep) {
    int guard = 0;
    while (ldw(p) < ep && ++guard < (1 << 18)) __builtin_amdgcn_s_sleep(2);
}

// acc[a][b] += sum_k L[a].k * R[k].b   (NN product step)
__device__ __forceinline__ void mm4x4(float (&acc)[4][4],
    float4 L0, float4 L1, float4 L2, float4 L3,
    float4 R0, float4 R1, float4 R2, float4 R3)
{
    const float L[4][4] = {{L0.x,L0.y,L0.z,L0.w},{L1.x,L1.y,L1.z,L1.w},
                           {L2.x,L2.y,L2.z,L2.w},{L3.x,L3.y,L3.z,L3.w}};
    const float R[4][4] = {{R0.x,R0.y,R0.z,R0.w},{R1.x,R1.y,R1.z,R1.w},
                           {R2.x,R2.y,R2.z,R2.w},{R3.x,R3.y,R3.z,R3.w}};
    #pragma unroll
    for (int a = 0; a < 4; a++)
        #pragma unroll
        for (int k = 0; k < 4; k++)
            #pragma unroll
            for (int b = 0; b < 4; b++)
                acc[a][b] += L[a][k] * R[k][b];
}

// acc[a][b] += sum_k L[a].k * R[b].k   (NT product step: A = Wq @ Wk^T)
__device__ __forceinline__ void mmNT4x4(float (&acc)[4][4],
    float4 L0, float4 L1, float4 L2, float4 L3,
    float4 R0, float4 R1, float4 R2, float4 R3)
{
    const float L[4][4] = {{L0.x,L0.y,L0.z,L0.w},{L1.x,L1.y,L1.z,L1.w},
                           {L2.x,L2.y,L2.z,L2.w},{L3.x,L3.y,L3.z,L3.w}};
    const float R[4][4] = {{R0.x,R0.y,R0.z,R0.w},{R1.x,R1.y,R1.z,R1.w},
                           {R2.x,R2.y,R2.z,R2.w},{R3.x,R3.y,R3.z,R3.w}};
    #pragma unroll
    for (int a = 0; a < 4; a++)
        #pragma unroll
        for (int b = 0; b < 4; b++)
            #pragma unroll
            for (int k = 0; k < 4; k++)
                acc[a][b] += L[a][k] * R[b][k];
}

// acc[a][b] += A.a * B.b
__device__ __forceinline__ void outer4x4(float (&acc)[4][4], float4 A, float4 B)
{
    const float Aa[4] = {A.x, A.y, A.z, A.w};
    const float Ba[4] = {B.x, B.y, B.z, B.w};
    #pragma unroll
    for (int a = 0; a < 4; a++)
        #pragma unroll
        for (int b = 0; b < 4; b++)
            acc[a][b] += Aa[a] * Ba[b];
}

// LDS layout (floats):
//   sH  [32][68]  @ 0      resident h rows
//   B1  [64][68]  @ 2176   Wq -> Wv
//   B2  [64][68]  @ 6528   A (shadow-computed, persists through weff)
//   B3  [64][68]  @ 10880  partial-pack / combine-red / G / weff
//   B4  [64][68]  @ 15232  Wk -> Wb
//   B5  [64][68]  @ 19584  T'
//   smalls @ 23936..24511 ; red [4][64] @ 24512
// total 24768 floats = 99072 B -> 1 block/CU, 256 blocks co-resident.

#define SM_SS   23936
#define SM_SU   24000
#define SM_BK   24064
#define SM_BQ   24128
#define SM_BV   24192
#define SM_BE   24256
#define SM_QK   24320
#define SM_KQ   24384
#define SM_QBK  24448
#define SM_RED  24512
#define SM_TOT  24768

template <typename T>
__device__ void run_net(
    const void* x, const void* lw, const void* lb,
    const void* blkw, const void* blkb,
    const void* qw, const void* qb, const void* kw, const void* kb,
    const void* vw, const void* vb, const void* pw, const void* pb,
    void* out, float* Gpart, float* Gg,
    unsigned* aflag, unsigned* cflag,
    float* smem, int blk, int t)
{
    float (*sH)[SHP] = (float(*)[SHP])(smem);
    float (*B1)[SHP] = (float(*)[SHP])(smem + 2176);
    float (*B2)[SHP] = (float(*)[SHP])(smem + 6528);
    float (*B3)[SHP] = (float(*)[SHP])(smem + 10880);
    float (*B4)[SHP] = (float(*)[SHP])(smem + 15232);
    float (*B5)[SHP] = (float(*)[SHP])(smem + 19584);
    float* PS  = smem + 10880;          // packed-partial scratch (aliases B3)
    float* RED = smem + 10880;          // combine reduction [16][20] (aliases B3)
    float* sS  = smem + SM_SS;
    float* suS = smem + SM_SU;
    float* bkS = smem + SM_BK;
    float* bqS = smem + SM_BQ;
    float* bvS = smem + SM_BV;
    float* beS = smem + SM_BE;
    float* qkS = smem + SM_QK;
    float* kqS = smem + SM_KQ;
    float* qbkS = smem + SM_QBK;
    float (*red)[DD] = (float(*)[DD])(smem + SM_RED);

    const int row0 = blk * RPB;
    const int bb = blk >> 7;                      // batch of this block
    const int r = t >> 4, c4 = (t & 15) << 2;     // apply/lift mapping
    const int i4 = t >> 4, j4 = t & 15;           // 4x4 tile grid coords
    const int r0 = i4 << 2, c0 = j4 << 2;

    // ---- lift: 32 rows of h into resident LDS ----
    #pragma unroll
    for (int a = 0; a < 2; a++) {
        const int row = r + 16 * a, gr = row0 + row;
        float x0 = Acc<T>::ld(x, gr * 3 + 0);
        float x1 = Acc<T>::ld(x, gr * 3 + 1);
        float x2 = Acc<T>::ld(x, gr * 3 + 2);
        float o[4];
        #pragma unroll
        for (int b = 0; b < 4; b++) {
            int c = c4 + b;
            o[b] = Acc<T>::ld(lb, c) + x0 * Acc<T>::ld(lw, c)
                 + x1 * Acc<T>::ld(lw, DD + c) + x2 * Acc<T>::ld(lw, 2 * DD + c);
        }
        *(float4*)&sH[row][c4] = make_float4(o[0], o[1], o[2], o[3]);
    }
    __syncthreads();

    for (int layer = 0; layer < NLAYER; layer++) {
        const unsigned ep = (unsigned)(layer + 1);
        float* GgL = Gg + (size_t)(layer * NB + bb) * PSZ;
        const int wOff = layer * DD * DD, bOff = layer * DD;

        // ---- A: packed symmetric G-partial (upper triangle) into PS ----
        {
            if (i4 <= j4) {
                float m[4][4];
                #pragma unroll
                for (int a = 0; a < 4; a++)
                    #pragma unroll
                    for (int b = 0; b < 4; b++) m[a][b] = 0.f;
                #pragma unroll 8
                for (int n = 0; n < RPB; n++)
                    outer4x4(m, *(const float4*)&sH[n][r0], *(const float4*)&sH[n][c0]);
                float* dst = PS + (i4 * (33 - i4) / 2 + (j4 - i4)) * 16;
                #pragma unroll
                for (int a = 0; a < 4; a++)
                    #pragma unroll
                    for (int b = 0; b < 4; b++) dst[a * 4 + b] = m[a][b];
            }
            if (t < DD) {
                float ss = 0.f;
                #pragma unroll 8
                for (int n = 0; n < RPB; n++) ss += sH[n][t];
                PS[2176 + t] = ss;
                PS[2240 + t] = 0.f;     // pad (combine reduces it blindly)
            }
        }
        __syncthreads();
        // ---- B: wave-linear coherent copy PS -> own Gpart slot ----
        {
            float* slot = Gpart + (size_t)blk * PSZ;
            #pragma unroll
            for (int k2 = 0; k2 < 4; k2++) {
                const int idx = 2 * (t + k2 * NT);
                stc2(&slot[idx], PS[idx], PS[idx + 1]);
            }
            if (t < 128) {
                const int idx = 2 * (t + 4 * NT);
                stc2(&slot[idx], PS[idx], PS[idx + 1]);
            }
        }
        __syncthreads();                // vmcnt(0) per wave: partial fully visible
        if (t == 0) stw(&aflag[blk], ep);

        // ---- C: stage Wq/Wk + bias vectors while producers finish ----
        for (int i2 = t; i2 < DD * DD; i2 += NT) {
            B1[i2 >> 6][i2 & 63] = Acc<T>::ld(qw, wOff + i2);
            B4[i2 >> 6][i2 & 63] = Acc<T>::ld(kw, wOff + i2);
        }
        if (t < DD) {
            bkS[t] = Acc<T>::ld(kb, bOff + t);
            bqS[t] = Acc<T>::ld(qb, bOff + t);
            bvS[t] = Acc<T>::ld(vb, bOff + t);
        }

        // ---- D: combine own chunk across 128 slots of own batch ----
        {
            if (t < NCH) pollw(&aflag[bb * NCH + t], ep);
            __syncthreads();            // C staging complete + all partials seen
            const int chunk = blk & (NCH - 1);
            if (t < 144) {
                const int g = t / 9, p2 = t % 9;    // 16 slot-groups x 9 pairs
                const float* base = Gpart + (size_t)(bb * NCH + g * 8) * PSZ
                                  + chunk * CHW + 2 * p2;
                float ax = 0.f, ay = 0.f;
                #pragma unroll
                for (int s2 = 0; s2 < 8; s2++) {
                    float2 v = ldc2(base + (size_t)s2 * PSZ);
                    ax += v.x; ay += v.y;
                }
                RED[g * 20 + 2 * p2]     = ax;
                RED[g * 20 + 2 * p2 + 1] = ay;
            }
            __syncthreads();
            if (t < 9) {
                float s0 = 0.f, s1 = 0.f;
                #pragma unroll
                for (int g = 0; g < 16; g++) {
                    s0 += RED[g * 20 + 2 * t];
                    s1 += RED[g * 20 + 2 * t + 1];
                }
                stc2(&GgL[chunk * CHW + 2 * t], s0, s1);
            }
            __syncthreads();            // Gg stores drained
            if (t == 0) stw(&cflag[blk], ep);
        }

        // ---- E (cflag shadow): A = Wq@Wk^T, qk, kq, qbk; then Wv/Wb stage ----
        {
            float acc[4][4];
            #pragma unroll
            for (int a = 0; a < 4; a++)
                #pragma unroll
                for (int b = 0; b < 4; b++) acc[a][b] = 0.f;
            #pragma unroll 2
            for (int e = 0; e < DD; e += 4)
                mmNT4x4(acc,
                      *(const float4*)&B1[r0 + 0][e], *(const float4*)&B1[r0 + 1][e],
                      *(const float4*)&B1[r0 + 2][e], *(const float4*)&B1[r0 + 3][e],
                      *(const float4*)&B4[c0 + 0][e], *(const float4*)&B4[c0 + 1][e],
                      *(const float4*)&B4[c0 + 2][e], *(const float4*)&B4[c0 + 3][e]);
            #pragma unroll
            for (int a = 0; a < 4; a++)
                *(float4*)&B2[r0 + a][c0] = make_float4(acc[a][0], acc[a][1], acc[a][2], acc[a][3]);

            if (t < DD) {               // qk = Wq@bk
                float u = 0.f;
                for (int e = 0; e < DD; e++) u += B1[t][e] * bkS[e];
                qkS[t] = u;
            } else if (t < 2 * DD) {    // kq = Wk@bq
                const int rr = t - DD;
                float u = 0.f;
                for (int e = 0; e < DD; e++) u += B4[rr][e] * bqS[e];
                kqS[rr] = u;
            } else if (t == 2 * DD) {   // qbk = bq.bk
                float u = 0.f;
                for (int e = 0; e < DD; e++) u += bqS[e] * bkS[e];
                qbkS[0] = u;
            }
        }
        __syncthreads();                // B1/B4 free
        for (int i2 = t; i2 < DD * DD; i2 += NT) {
            B1[i2 >> 6][i2 & 63] = Acc<T>::ld(vw, wOff + i2);
            B4[i2 >> 6][i2 & 63] = Acc<T>::ld(blkw, wOff + i2);
        }

        // ---- F: wait all 128 chunks; stage G -> B3 (mirrored) ----
        {
            if (t < NCH) pollw(&cflag[bb * NCH + t], ep);
            __syncthreads();            // staging done + G visible
            // per-layer Gg + release-before-flag => normal CACHED loads safe
            if (i4 <= j4) {
                const float* src = GgL + (i4 * (33 - i4) / 2 + (j4 - i4)) * 16;
                #pragma unroll
                for (int a = 0; a < 4; a++)
                    *(float4*)&B3[r0 + a][c0] = *(const float4*)&src[a * 4];
            } else {
                const float* src = GgL + (j4 * (33 - j4) / 2 + (i4 - j4)) * 16;
                #pragma unroll
                for (int a = 0; a < 4; a++)
                    #pragma unroll
                    for (int b = 0; b < 4; b++)
                        B3[r0 + a][c0 + b] = src[b * 4 + a];
            }
            if (t < DD) sS[t] = GgL[2176 + t];
            __syncthreads();
        }

        // ---- G: B5 = T' = G@Wv + s bv^T ; red = su partials ----
        {
            float acc[4][4];
            #pragma unroll
            for (int a = 0; a < 4; a++)
                #pragma unroll
                for (int b = 0; b < 4; b++) acc[a][b] = sS[r0 + a] * bvS[c0 + b];
            #pragma unroll 2
            for (int e = 0; e < DD; e += 4)
                mm4x4(acc,
                      *(const float4*)&B3[r0 + 0][e], *(const float4*)&B3[r0 + 1][e],
                      *(const float4*)&B3[r0 + 2][e], *(const float4*)&B3[r0 + 3][e],
                      *(const float4*)&B1[e + 0][c0], *(const float4*)&B1[e + 1][c0],
                      *(const float4*)&B1[e + 2][c0], *(const float4*)&B1[e + 3][c0]);
            #pragma unroll
            for (int a = 0; a < 4; a++)
                *(float4*)&B5[r0 + a][c0] = make_float4(acc[a][0], acc[a][1], acc[a][2], acc[a][3]);
        }
        {   // su[c] = sum_d s[d]*Wv[d][c] partials (4 k-groups x 64 cols)
            const int c = t & 63, q = t >> 6;
            float u = 0.f;
            #pragma unroll
            for (int d2 = 0; d2 < 16; d2++) u += sS[q * 16 + d2] * B1[q * 16 + d2][c];
            red[q][c] = u;
        }
        __syncthreads();
        if (t < DD) suS[t] = red[0][t] + red[1][t] + red[2][t] + red[3][t] + (float)NN * bvS[t];
        __syncthreads();

        // ---- H: B3 = weff = Wb + C0*(A@T' + qk su^T) ; red = beff partials ----
        {
            float acc[4][4];
            #pragma unroll
            for (int a = 0; a < 4; a++)
                #pragma unroll
                for (int b = 0; b < 4; b++) acc[a][b] = qkS[r0 + a] * suS[c0 + b];
            #pragma unroll 2
            for (int e = 0; e < DD; e += 4)
                mm4x4(acc,
                      *(const float4*)&B2[r0 + 0][e], *(const float4*)&B2[r0 + 1][e],
                      *(const float4*)&B2[r0 + 2][e], *(const float4*)&B2[r0 + 3][e],
                      *(const float4*)&B5[e + 0][c0], *(const float4*)&B5[e + 1][c0],
                      *(const float4*)&B5[e + 2][c0], *(const float4*)&B5[e + 3][c0]);
            float wloc[4][4];
            #pragma unroll
            for (int a = 0; a < 4; a++)
                #pragma unroll
                for (int b = 0; b < 4; b++)
                    wloc[a][b] = B4[r0 + a][c0 + b] + C0F * acc[a][b];
            {   // beff partials BEFORE overwriting B3 (reads B5 only; safe)
                const int c = t & 63, q = t >> 6;
                float u = 0.f;
                #pragma unroll
                for (int e2 = 0; e2 < 16; e2++) u += kqS[q * 16 + e2] * B5[q * 16 + e2][c];
                red[q][c] = u;
            }
            __syncthreads();            // all G-reads of B3 done; red visible
            #pragma unroll
            for (int a = 0; a < 4; a++)
                *(float4*)&B3[r0 + a][c0] = make_float4(wloc[a][0], wloc[a][1], wloc[a][2], wloc[a][3]);
            if (t < DD) beS[t] = Acc<T>::ld(blkb, bOff + t)
                               + C0F * (red[0][t] + red[1][t] + red[2][t] + red[3][t]
                                        + qbkS[0] * suS[t]);
        }
        __syncthreads();

        // ---- apply: h' = gelu(h@weff + beff) on resident rows ----
        float o[2][4];
        #pragma unroll
        for (int a = 0; a < 2; a++) {
            const int row = r + 16 * a;
            float acc2[4];
            #pragma unroll
            for (int b = 0; b < 4; b++) acc2[b] = beS[c4 + b];
            for (int d = 0; d < DD; d++) {
                float hv = sH[row][d];
                float4 w4 = *(const float4*)&B3[d][c4];
                acc2[0] += hv * w4.x; acc2[1] += hv * w4.y;
                acc2[2] += hv * w4.z; acc2[3] += hv * w4.w;
            }
            #pragma unroll
            for (int b = 0; b < 4; b++) o[a][b] = gelu_exact(acc2[b]);
        }

        if (layer == NLAYER - 1) {
            float pbv = Acc<T>::ld(pb, 0);
            #pragma unroll
            for (int a = 0; a < 2; a++) {
                float p = 0.f;
                #pragma unroll
                for (int b = 0; b < 4; b++) p += o[a][b] * Acc<T>::ld(pw, c4 + b);
                p += __shfl_xor(p, 1);
                p += __shfl_xor(p, 2);
                p += __shfl_xor(p, 4);
                p += __shfl_xor(p, 8);
                if ((t & 15) == 0) Acc<T>::st(out, row0 + r + 16 * a, p + pbv);
            }
        } else {
            __syncthreads();    // weff/beS/sH reads done before sH overwrite
            #pragma unroll
            for (int a = 0; a < 2; a++)
                *(float4*)&sH[r + 16 * a][c4] =
                    make_float4(o[a][0], o[a][1], o[a][2], o[a][3]);
            __syncthreads();
        }
    }
}

__global__ __launch_bounds__(NT) void gno_kernel(
    const void* x, const void* lw, const void* lb,
    const void* blkw, const void* blkb,
    const void* qw, const void* qb, const void* kw, const void* kb,
    const void* vw, const void* vb, const void* pw, const void* pb,
    void* out, float* Gpart, float* Gg, unsigned* bar, int mode)
{
    __shared__ alignas(16) float smem[SM_TOT];   // 99072 B
    __shared__ int stot;

    const int blk = blockIdx.x, t = threadIdx.x;

    bool isbf;
    if (mode >= 0) {
        isbf = (mode == 1);
    } else {
        // fallback: device dtype scan (same result in every block)
        if (t == 0) stot = 0;
        __syncthreads();
        int cdt = 0;
        const unsigned int* xw = (const unsigned int*)x;
        for (int i = t; i < 8192; i += NT) {
            unsigned u = xw[i] & 0xFFFFu;
            int e = (u >> 7) & 0xFF;
            cdt += (u == 0u || (e >= 100 && e <= 142)) ? 1 : 0;
        }
        atomicAdd(&stot, cdt);
        __syncthreads();
        isbf = (stot > 4915);
    }

    unsigned* aflag = bar;          // [256] producer epochs
    unsigned* cflag = bar + 256;    // [256] combine epochs

    if (isbf)
        run_net<bf16>(x, lw, lb, blkw, blkb, qw, qb, kw, kb, vw, vb, pw, pb,
                      out, Gpart, Gg, aflag, cflag, smem, blk, t);
    else
        run_net<float>(x, lw, lb, blkw, blkb, qw, qb, kw, kb, vw, vb, pw, pb,
                       out, Gpart, Gg, aflag, cflag, smem, blk, t);
}

extern "C" void kernel_launch(void* const* d_in, const int* in_sizes, int n_in,
                              void* d_out, int out_size, void* d_ws, size_t ws_size,
                              hipStream_t stream)
{
    const void* x    = d_in[0];
    const void* lw   = d_in[1];
    const void* lb   = d_in[2];
    const void* blkw = d_in[3];
    const void* blkb = d_in[4];
    const void* qw   = d_in[5];
    const void* qb   = d_in[6];
    const void* kw   = d_in[7];
    const void* kb   = d_in[8];
    const void* vw   = d_in[9];
    const void* vb   = d_in[10];
    const void* pw   = d_in[11];
    const void* pb   = d_in[12];

    // x = [2,64,64,3]: fp32 -> 98304 B, bf16 -> 49152 B
    int mode = -1;
    if (in_sizes && n_in > 0) {
        if (in_sizes[0] == 49152) mode = 1;
        else if (in_sizes[0] == 98304) mode = 0;
    }

    unsigned* bar = (unsigned*)d_ws;                      // [512] flag words
    float* Gpart  = (float*)d_ws + 512;                   // [256][2304] 2.36 MB
    float* Gg     = Gpart + (size_t)NBLK * PSZ;           // [4][2][2304] per-layer

    (void)hipMemsetAsync(bar, 0, 512 * sizeof(unsigned), stream);
    gno_kernel<<<NBLK, NT, 0, stream>>>(x, lw, lb, blkw, blkb, qw, qb, kw, kb,
                                        vw, vb, pw, pb, d_out, Gpart, Gg, bar, mode);
}